// Round 4
// baseline (571.067 us; speedup 1.0000x reference)
//
#include <hip/hip_runtime.h>

// ---------------------------------------------------------------------------
// BipartiteLayer: xp = x@W_in+b ; s = exp(-|[xp_i[s],xp_m[e]]@W_score+b|) ;
// scatter mean/max of xp_pair*s ; h = relu([x,xp,mean,max]@W_out+b)
//
// Pipeline (slab-chunked H to fit adaptive workspace):
//   k_prep_wt   : W_out (1408x128 f32) -> Wt (128x1408 bf16) transpose
//   k_gemm_in   : f32 vector GEMM -> xp (bf16) + fused a = xp . W_score_half
//   k_edge      : per-edge score + linked-list CSR build (atomicExch)
//   per slab:
//     k_agg     : wave-per-node gather-reduce -> H slab rows (1408 bf16)
//     k_gemm_out: bf16 MFMA 16x16x32, K=1408, N=128, bias+relu epilogue
// Fixed scratch = 56.7 MB; H slab sized from remaining ws_size.
// ---------------------------------------------------------------------------

typedef __attribute__((ext_vector_type(8))) short bf16x8;   // 8 bf16 = 4 VGPR
typedef __attribute__((ext_vector_type(4))) float f32x4;

static __device__ __forceinline__ unsigned short f2bf(float f) {
  unsigned int u = __float_as_uint(f);
  u = (u + 0x7FFFu + ((u >> 16) & 1u)) >> 16;   // RNE
  return (unsigned short)u;
}
static __device__ __forceinline__ float bf2f(unsigned short s) {
  return __uint_as_float(((unsigned int)s) << 16);
}

// ---- transpose W_out -> Wt[col][k] bf16 -----------------------------------
__global__ void k_prep_wt(const float* __restrict__ Wo,
                          unsigned short* __restrict__ Wt, int K, int Ncol) {
  int idx = blockIdx.x * blockDim.x + threadIdx.x;
  if (idx >= K * Ncol) return;
  int k = idx / Ncol, c = idx % Ncol;
  Wt[(size_t)c * K + k] = f2bf(Wo[idx]);
}

// ---- input GEMM: [N,128] @ [128,256] + b -> xp bf16; fused a = xp.Ws ------
// block = 256 = 4 waves; wave handles 8 rows; lane handles 4 cols
__global__ __launch_bounds__(256) void k_gemm_in(
    const float* __restrict__ x, const float* __restrict__ W,
    const float* __restrict__ bias, const float* __restrict__ Wsc,
    unsigned short* __restrict__ xp, float* __restrict__ a_out, int N) {
  int w = threadIdx.x >> 6, l = threadIdx.x & 63;
  int rbase = blockIdx.x * 32 + w * 8;
  if (rbase >= N) return;                       // wave-uniform
  int rows[8];
#pragma unroll
  for (int r = 0; r < 8; ++r) rows[r] = min(rbase + r, N - 1);
  float acc[8][4];
#pragma unroll
  for (int r = 0; r < 8; ++r)
#pragma unroll
    for (int c = 0; c < 4; ++c) acc[r][c] = 0.f;

  for (int k4 = 0; k4 < 32; ++k4) {
    float4 wv[4];
#pragma unroll
    for (int j = 0; j < 4; ++j)
      wv[j] = *(const float4*)(W + (size_t)(k4 * 4 + j) * 256 + 4 * l);
#pragma unroll
    for (int r = 0; r < 8; ++r) {
      float4 xv = *(const float4*)(x + (size_t)rows[r] * 128 + 4 * k4);
#pragma unroll
      for (int j = 0; j < 4; ++j) {
        float xk = (j == 0) ? xv.x : (j == 1) ? xv.y : (j == 2) ? xv.z : xv.w;
        acc[r][0] = fmaf(xk, wv[j].x, acc[r][0]);
        acc[r][1] = fmaf(xk, wv[j].y, acc[r][1]);
        acc[r][2] = fmaf(xk, wv[j].z, acc[r][2]);
        acc[r][3] = fmaf(xk, wv[j].w, acc[r][3]);
      }
    }
  }
  float4 bv = *(const float4*)(bias + 4 * l);
  float4 wsv = *(const float4*)(Wsc + 4 * l);
#pragma unroll
  for (int r = 0; r < 8; ++r) {
    int g = rbase + r;
    if (g < N) {                                 // wave-uniform
      float v0 = acc[r][0] + bv.x, v1 = acc[r][1] + bv.y;
      float v2 = acc[r][2] + bv.z, v3 = acc[r][3] + bv.w;
      *(ushort4*)(xp + (size_t)g * 256 + 4 * l) =
          make_ushort4(f2bf(v0), f2bf(v1), f2bf(v2), f2bf(v3));
      float p = v0 * wsv.x + v1 * wsv.y + v2 * wsv.z + v3 * wsv.w;
#pragma unroll
      for (int off = 32; off; off >>= 1) p += __shfl_xor(p, off);
      if (l == 0) a_out[g] = p;
    }
  }
}

// ---- per-edge score + linked-list CSR -------------------------------------
__global__ void k_edge(const int* __restrict__ es, const int* __restrict__ ee,
                       int E, const float* __restrict__ a_i,
                       const float* __restrict__ a_m,
                       const float* __restrict__ bsc,
                       float* __restrict__ slist, int* __restrict__ head_i,
                       int* __restrict__ next_i, int* __restrict__ head_m,
                       int* __restrict__ next_m) {
  int e = blockIdx.x * blockDim.x + threadIdx.x;
  if (e >= E) return;
  int s = es[e], m = ee[e];
  float t = a_i[s] + a_m[m] + bsc[0];
  slist[e] = expf(-fabsf(t));
  next_i[e] = atomicExch(head_i + s, e);
  next_m[e] = atomicExch(head_m + m, e);
}

// ---- wave-per-node aggregation -> H slab row (1408 bf16) ------------------
// H = [x(128) | xp(256) | mean(512) | max(512)]
// own half of mean/max = xp_own * {sum,max,min}(s); other half gathered.
__global__ __launch_bounds__(256) void k_agg(
    const float* __restrict__ x_own, const unsigned short* __restrict__ xp_own,
    const unsigned short* __restrict__ xp_oth, const int* __restrict__ head,
    const int* __restrict__ nxt, const int* __restrict__ oth_id,
    const float* __restrict__ slist, unsigned short* __restrict__ H,
    int base, int cnt, int own_off, int oth_off) {
  int local = blockIdx.x * 4 + (threadIdx.x >> 6);
  if (local >= cnt) return;                      // wave-uniform
  int node = base + local;
  int l = threadIdx.x & 63;
  ushort4 xo = *(const ushort4*)(xp_own + (size_t)node * 256 + 4 * l);
  float xp0 = bf2f(xo.x), xp1 = bf2f(xo.y), xp2 = bf2f(xo.z), xp3 = bf2f(xo.w);
  float2 xv = *(const float2*)(x_own + (size_t)node * 128 + 2 * l);
  unsigned short* Hr = H + (size_t)local * 1408;
  *(ushort2*)(Hr + 2 * l) = make_ushort2(f2bf(xv.x), f2bf(xv.y));
  *(ushort4*)(Hr + 128 + 4 * l) = xo;

  float sum_s = 0.f, mx_s = -1e30f, mn_s = 1e30f;
  float sv0 = 0.f, sv1 = 0.f, sv2 = 0.f, sv3 = 0.f;
  float mv0 = -1e30f, mv1 = -1e30f, mv2 = -1e30f, mv3 = -1e30f;
  int dg = 0;
  for (int e = head[node]; e >= 0; e = nxt[e]) {   // uniform chain walk
    int o = oth_id[e];
    float s = slist[e];
    ushort4 ov = *(const ushort4*)(xp_oth + (size_t)o * 256 + 4 * l);
    float f0 = bf2f(ov.x), f1 = bf2f(ov.y), f2 = bf2f(ov.z), f3 = bf2f(ov.w);
    sv0 = fmaf(s, f0, sv0); sv1 = fmaf(s, f1, sv1);
    sv2 = fmaf(s, f2, sv2); sv3 = fmaf(s, f3, sv3);
    mv0 = fmaxf(mv0, s * f0); mv1 = fmaxf(mv1, s * f1);
    mv2 = fmaxf(mv2, s * f2); mv3 = fmaxf(mv3, s * f3);
    sum_s += s; mx_s = fmaxf(mx_s, s); mn_s = fminf(mn_s, s);
    ++dg;
  }
  float inv = 1.f / (float)(dg > 0 ? dg : 1);
  float ss = sum_s * inv;
  *(ushort4*)(Hr + 384 + own_off + 4 * l) = make_ushort4(
      f2bf(xp0 * ss), f2bf(xp1 * ss), f2bf(xp2 * ss), f2bf(xp3 * ss));
  *(ushort4*)(Hr + 384 + oth_off + 4 * l) = make_ushort4(
      f2bf(sv0 * inv), f2bf(sv1 * inv), f2bf(sv2 * inv), f2bf(sv3 * inv));
  float a0, a1, a2, a3;
  if (dg > 0) {
    a0 = fmaxf(fmaxf(xp0 * mx_s, xp0 * mn_s), 0.f);
    a1 = fmaxf(fmaxf(xp1 * mx_s, xp1 * mn_s), 0.f);
    a2 = fmaxf(fmaxf(xp2 * mx_s, xp2 * mn_s), 0.f);
    a3 = fmaxf(fmaxf(xp3 * mx_s, xp3 * mn_s), 0.f);
  } else {
    a0 = a1 = a2 = a3 = 0.f;
  }
  *(ushort4*)(Hr + 896 + own_off + 4 * l) =
      make_ushort4(f2bf(a0), f2bf(a1), f2bf(a2), f2bf(a3));
  *(ushort4*)(Hr + 896 + oth_off + 4 * l) =
      make_ushort4(f2bf(fmaxf(mv0, 0.f)), f2bf(fmaxf(mv1, 0.f)),
                   f2bf(fmaxf(mv2, 0.f)), f2bf(fmaxf(mv3, 0.f)));
}

// ---- output GEMM: [cnt,1408]bf16 @ [1408,128]bf16 + b, relu -> f32 --------
// block = 256 = 4 waves * 32 rows = 128 rows/block; wave: 2 row x 8 col frags
__global__ __launch_bounds__(256) void k_gemm_out(
    const unsigned short* __restrict__ H, const unsigned short* __restrict__ Wt,
    const float* __restrict__ bias, float* __restrict__ out, int Nloc) {
  int w = threadIdx.x >> 6, l = threadIdx.x & 63;
  int lr = l & 15, lg = l >> 4;
  int r0 = blockIdx.x * 128 + w * 32;
  f32x4 acc[2][8];
#pragma unroll
  for (int h = 0; h < 2; ++h)
#pragma unroll
    for (int t = 0; t < 8; ++t) {
      f32x4 z = {0.f, 0.f, 0.f, 0.f};
      acc[h][t] = z;
    }
  const unsigned short* A0 = H + (size_t)(r0 + lr) * 1408;
  const unsigned short* A1 = A0 + (size_t)16 * 1408;
#pragma unroll 2
  for (int kc = 0; kc < 44; ++kc) {
    int kb = kc * 32 + lg * 8;
    bf16x8 a0 = *(const bf16x8*)(A0 + kb);
    bf16x8 a1 = *(const bf16x8*)(A1 + kb);
#pragma unroll
    for (int t = 0; t < 8; ++t) {
      bf16x8 bt = *(const bf16x8*)(Wt + (size_t)(t * 16 + lr) * 1408 + kb);
      acc[0][t] = __builtin_amdgcn_mfma_f32_16x16x32_bf16(a0, bt, acc[0][t], 0, 0, 0);
      acc[1][t] = __builtin_amdgcn_mfma_f32_16x16x32_bf16(a1, bt, acc[1][t], 0, 0, 0);
    }
  }
#pragma unroll
  for (int h = 0; h < 2; ++h) {
    int rbase = r0 + h * 16 + lg * 4;   // C/D: col=lane&15, row=(lane>>4)*4+reg
#pragma unroll
    for (int t = 0; t < 8; ++t) {
      int c = t * 16 + lr;
      float bb = bias[c];
#pragma unroll
      for (int r = 0; r < 4; ++r) {
        int rr = rbase + r;
        if (rr < Nloc) out[(size_t)rr * 128 + c] = fmaxf(acc[h][t][r] + bb, 0.f);
      }
    }
  }
}

extern "C" void kernel_launch(void* const* d_in, const int* in_sizes, int n_in,
                              void* d_out, int out_size, void* d_ws,
                              size_t ws_size, hipStream_t stream) {
  const float* x_i  = (const float*)d_in[0];
  const float* x_m  = (const float*)d_in[1];
  const int*   ei   = (const int*)d_in[2];
  const float* Wi_i = (const float*)d_in[3];
  const float* bi_i = (const float*)d_in[4];
  const float* Wi_m = (const float*)d_in[5];
  const float* bi_m = (const float*)d_in[6];
  const float* Wsc  = (const float*)d_in[7];
  const float* bsc  = (const float*)d_in[8];
  const float* Wo_i = (const float*)d_in[9];
  const float* bo_i = (const float*)d_in[10];
  const float* Wo_m = (const float*)d_in[11];
  const float* bo_m = (const float*)d_in[12];
  float* out = (float*)d_out;

  int Ni = in_sizes[0] / 128, Nm = in_sizes[1] / 128, E = in_sizes[2] / 2;
  const int* es = ei;
  const int* ee = ei + E;

  char* p = (char*)d_ws;
  auto alloc = [&](size_t bytes) {
    char* q = p;
    p += (bytes + 255) & ~(size_t)255;
    return q;
  };
  unsigned short* xp_i = (unsigned short*)alloc((size_t)Ni * 256 * 2);
  unsigned short* xp_m = (unsigned short*)alloc((size_t)Nm * 256 * 2);
  float* a_i   = (float*)alloc((size_t)Ni * 4);
  float* a_m   = (float*)alloc((size_t)Nm * 4);
  float* slist = (float*)alloc((size_t)E * 4);
  int* head_i  = (int*)alloc((size_t)Ni * 4);
  int* head_m  = (int*)alloc((size_t)Nm * 4);
  int* next_i  = (int*)alloc((size_t)E * 4);
  int* next_m  = (int*)alloc((size_t)E * 4);
  unsigned short* Wt_i = (unsigned short*)alloc((size_t)128 * 1408 * 2);
  unsigned short* Wt_m = (unsigned short*)alloc((size_t)128 * 1408 * 2);

  size_t used = (size_t)(p - (char*)d_ws);
  if (used + 256 > ws_size) return;              // hopeless: fixed scratch alone
  // H slab: as many 1408-bf16 rows as fit, multiple of 128
  size_t avail = ws_size - used - 256;
  long long srows_ll = (long long)(avail / (1408 * 2));
  int maxN = (Ni > Nm ? Ni : Nm);
  int maxPad = (maxN + 127) & ~127;
  int S = (int)(srows_ll > maxPad ? maxPad : srows_ll);
  S &= ~127;
  if (S < 128) return;                           // cannot fit a single tile
  unsigned short* Hs = (unsigned short*)alloc((size_t)S * 1408 * 2);

  hipMemsetAsync(head_i, 0xFF, (size_t)Ni * 4, stream);
  hipMemsetAsync(head_m, 0xFF, (size_t)Nm * 4, stream);

  k_prep_wt<<<(1408 * 128 + 255) / 256, 256, 0, stream>>>(Wo_i, Wt_i, 1408, 128);
  k_prep_wt<<<(1408 * 128 + 255) / 256, 256, 0, stream>>>(Wo_m, Wt_m, 1408, 128);

  k_gemm_in<<<(Ni + 31) / 32, 256, 0, stream>>>(x_i, Wi_i, bi_i, Wsc, xp_i, a_i, Ni);
  k_gemm_in<<<(Nm + 31) / 32, 256, 0, stream>>>(x_m, Wi_m, bi_m, Wsc + 256, xp_m, a_m, Nm);

  k_edge<<<(E + 255) / 256, 256, 0, stream>>>(es, ee, E, a_i, a_m, bsc, slist,
                                              head_i, next_i, head_m, next_m);

  // intt side: own half of pooled cols at [0,256), gathered (mvtx) at [256,512)
  for (int base = 0; base < Ni; base += S) {
    int cnt = Ni - base; if (cnt > S) cnt = S;
    int cntPad = (cnt + 127) & ~127;
    k_agg<<<(cnt + 3) / 4, 256, 0, stream>>>(x_i, xp_i, xp_m, head_i, next_i,
                                             ee, slist, Hs, base, cnt, 0, 256);
    k_gemm_out<<<cntPad / 128, 256, 0, stream>>>(Hs, Wt_i, bo_i,
                                                 out + (size_t)base * 128, cnt);
  }
  // mvtx side: gathered (intt) at [0,256), own half at [256,512)
  float* out_m = out + (size_t)Ni * 128;
  for (int base = 0; base < Nm; base += S) {
    int cnt = Nm - base; if (cnt > S) cnt = S;
    int cntPad = (cnt + 127) & ~127;
    k_agg<<<(cnt + 3) / 4, 256, 0, stream>>>(x_m, xp_m, xp_i, head_m, next_m,
                                             es, slist, Hs, base, cnt, 256, 0);
    k_gemm_out<<<cntPad / 128, 256, 0, stream>>>(Hs, Wt_m, bo_m,
                                                 out_m + (size_t)base * 128, cnt);
  }
}

// Round 5
// 459.495 us; speedup vs baseline: 1.2428x; 1.2428x over previous
//
#include <hip/hip_runtime.h>

// ---------------------------------------------------------------------------
// BipartiteLayer: xp = x@W_in+b ; s = exp(-|[xp_i[s],xp_m[e]]@W_score+b|) ;
// scatter mean/max of xp_pair*s ; h = relu([x,xp,mean,max]@W_out+b)
//
// Pipeline (slab-chunked H to fit adaptive workspace):
//   k_prep_wt   : W_out (1408x128 f32) -> Wt (128x1408 bf16) transpose
//   k_gemm_in   : f32 vector GEMM -> xp (bf16) + fused a = xp . W_score_half
//   k_edge      : per-edge score + linked-list CSR build (atomicExch)
//   per slab:
//     k_agg     : wave-per-node gather-reduce -> H slab rows (1408 bf16)
//     k_gemm_out: bf16 MFMA 16x16x32, 64x128 tile, BK=64 dbuf LDS via
//                 global_load_lds (pre-swizzled source + XOR-swizzled reads)
// ---------------------------------------------------------------------------

typedef __attribute__((ext_vector_type(8))) short bf16x8;   // 8 bf16 = 4 VGPR
typedef __attribute__((ext_vector_type(4))) float f32x4;

static __device__ __forceinline__ unsigned short f2bf(float f) {
  unsigned int u = __float_as_uint(f);
  u = (u + 0x7FFFu + ((u >> 16) & 1u)) >> 16;   // RNE
  return (unsigned short)u;
}
static __device__ __forceinline__ float bf2f(unsigned short s) {
  return __uint_as_float(((unsigned int)s) << 16);
}

#define GLD16(gp, lp)                                                        \
  __builtin_amdgcn_global_load_lds(                                          \
      (const __attribute__((address_space(1))) void*)(gp),                   \
      (__attribute__((address_space(3))) void*)(lp), 16, 0, 0)

// ---- transpose W_out -> Wt[col][k] bf16 -----------------------------------
__global__ void k_prep_wt(const float* __restrict__ Wo,
                          unsigned short* __restrict__ Wt, int K, int Ncol) {
  int idx = blockIdx.x * blockDim.x + threadIdx.x;
  if (idx >= K * Ncol) return;
  int k = idx / Ncol, c = idx % Ncol;
  Wt[(size_t)c * K + k] = f2bf(Wo[idx]);
}

// ---- input GEMM: [N,128] @ [128,256] + b -> xp bf16; fused a = xp.Ws ------
__global__ __launch_bounds__(256) void k_gemm_in(
    const float* __restrict__ x, const float* __restrict__ W,
    const float* __restrict__ bias, const float* __restrict__ Wsc,
    unsigned short* __restrict__ xp, float* __restrict__ a_out, int N) {
  int w = threadIdx.x >> 6, l = threadIdx.x & 63;
  int rbase = blockIdx.x * 32 + w * 8;
  if (rbase >= N) return;                       // wave-uniform
  int rows[8];
#pragma unroll
  for (int r = 0; r < 8; ++r) rows[r] = min(rbase + r, N - 1);
  float acc[8][4];
#pragma unroll
  for (int r = 0; r < 8; ++r)
#pragma unroll
    for (int c = 0; c < 4; ++c) acc[r][c] = 0.f;

  for (int k4 = 0; k4 < 32; ++k4) {
    float4 wv[4];
#pragma unroll
    for (int j = 0; j < 4; ++j)
      wv[j] = *(const float4*)(W + (size_t)(k4 * 4 + j) * 256 + 4 * l);
#pragma unroll
    for (int r = 0; r < 8; ++r) {
      float4 xv = *(const float4*)(x + (size_t)rows[r] * 128 + 4 * k4);
#pragma unroll
      for (int j = 0; j < 4; ++j) {
        float xk = (j == 0) ? xv.x : (j == 1) ? xv.y : (j == 2) ? xv.z : xv.w;
        acc[r][0] = fmaf(xk, wv[j].x, acc[r][0]);
        acc[r][1] = fmaf(xk, wv[j].y, acc[r][1]);
        acc[r][2] = fmaf(xk, wv[j].z, acc[r][2]);
        acc[r][3] = fmaf(xk, wv[j].w, acc[r][3]);
      }
    }
  }
  float4 bv = *(const float4*)(bias + 4 * l);
  float4 wsv = *(const float4*)(Wsc + 4 * l);
#pragma unroll
  for (int r = 0; r < 8; ++r) {
    int g = rbase + r;
    if (g < N) {                                 // wave-uniform
      float v0 = acc[r][0] + bv.x, v1 = acc[r][1] + bv.y;
      float v2 = acc[r][2] + bv.z, v3 = acc[r][3] + bv.w;
      *(ushort4*)(xp + (size_t)g * 256 + 4 * l) =
          make_ushort4(f2bf(v0), f2bf(v1), f2bf(v2), f2bf(v3));
      float p = v0 * wsv.x + v1 * wsv.y + v2 * wsv.z + v3 * wsv.w;
#pragma unroll
      for (int off = 32; off; off >>= 1) p += __shfl_xor(p, off);
      if (l == 0) a_out[g] = p;
    }
  }
}

// ---- per-edge score + linked-list CSR -------------------------------------
__global__ void k_edge(const int* __restrict__ es, const int* __restrict__ ee,
                       int E, const float* __restrict__ a_i,
                       const float* __restrict__ a_m,
                       const float* __restrict__ bsc,
                       float* __restrict__ slist, int* __restrict__ head_i,
                       int* __restrict__ next_i, int* __restrict__ head_m,
                       int* __restrict__ next_m) {
  int e = blockIdx.x * blockDim.x + threadIdx.x;
  if (e >= E) return;
  int s = es[e], m = ee[e];
  float t = a_i[s] + a_m[m] + bsc[0];
  slist[e] = expf(-fabsf(t));
  next_i[e] = atomicExch(head_i + s, e);
  next_m[e] = atomicExch(head_m + m, e);
}

// ---- wave-per-node aggregation -> H slab row (1408 bf16) ------------------
// H = [x(128) | xp(256) | mean(512) | max(512)]
__global__ __launch_bounds__(256) void k_agg(
    const float* __restrict__ x_own, const unsigned short* __restrict__ xp_own,
    const unsigned short* __restrict__ xp_oth, const int* __restrict__ head,
    const int* __restrict__ nxt, const int* __restrict__ oth_id,
    const float* __restrict__ slist, unsigned short* __restrict__ H,
    int base, int cnt, int own_off, int oth_off) {
  int local = blockIdx.x * 4 + (threadIdx.x >> 6);
  if (local >= cnt) return;                      // wave-uniform
  int node = base + local;
  int l = threadIdx.x & 63;
  ushort4 xo = *(const ushort4*)(xp_own + (size_t)node * 256 + 4 * l);
  float xp0 = bf2f(xo.x), xp1 = bf2f(xo.y), xp2 = bf2f(xo.z), xp3 = bf2f(xo.w);
  float2 xv = *(const float2*)(x_own + (size_t)node * 128 + 2 * l);
  unsigned short* Hr = H + (size_t)local * 1408;
  *(ushort2*)(Hr + 2 * l) = make_ushort2(f2bf(xv.x), f2bf(xv.y));
  *(ushort4*)(Hr + 128 + 4 * l) = xo;

  float sum_s = 0.f, mx_s = -1e30f, mn_s = 1e30f;
  float sv0 = 0.f, sv1 = 0.f, sv2 = 0.f, sv3 = 0.f;
  float mv0 = -1e30f, mv1 = -1e30f, mv2 = -1e30f, mv3 = -1e30f;
  int dg = 0;
  for (int e = head[node]; e >= 0; e = nxt[e]) {   // uniform chain walk
    int o = oth_id[e];
    float s = slist[e];
    ushort4 ov = *(const ushort4*)(xp_oth + (size_t)o * 256 + 4 * l);
    float f0 = bf2f(ov.x), f1 = bf2f(ov.y), f2 = bf2f(ov.z), f3 = bf2f(ov.w);
    sv0 = fmaf(s, f0, sv0); sv1 = fmaf(s, f1, sv1);
    sv2 = fmaf(s, f2, sv2); sv3 = fmaf(s, f3, sv3);
    mv0 = fmaxf(mv0, s * f0); mv1 = fmaxf(mv1, s * f1);
    mv2 = fmaxf(mv2, s * f2); mv3 = fmaxf(mv3, s * f3);
    sum_s += s; mx_s = fmaxf(mx_s, s); mn_s = fminf(mn_s, s);
    ++dg;
  }
  float inv = 1.f / (float)(dg > 0 ? dg : 1);
  float ss = sum_s * inv;
  *(ushort4*)(Hr + 384 + own_off + 4 * l) = make_ushort4(
      f2bf(xp0 * ss), f2bf(xp1 * ss), f2bf(xp2 * ss), f2bf(xp3 * ss));
  *(ushort4*)(Hr + 384 + oth_off + 4 * l) = make_ushort4(
      f2bf(sv0 * inv), f2bf(sv1 * inv), f2bf(sv2 * inv), f2bf(sv3 * inv));
  float a0, a1, a2, a3;
  if (dg > 0) {
    a0 = fmaxf(fmaxf(xp0 * mx_s, xp0 * mn_s), 0.f);
    a1 = fmaxf(fmaxf(xp1 * mx_s, xp1 * mn_s), 0.f);
    a2 = fmaxf(fmaxf(xp2 * mx_s, xp2 * mn_s), 0.f);
    a3 = fmaxf(fmaxf(xp3 * mx_s, xp3 * mn_s), 0.f);
  } else {
    a0 = a1 = a2 = a3 = 0.f;
  }
  *(ushort4*)(Hr + 896 + own_off + 4 * l) =
      make_ushort4(f2bf(a0), f2bf(a1), f2bf(a2), f2bf(a3));
  *(ushort4*)(Hr + 896 + oth_off + 4 * l) =
      make_ushort4(f2bf(fmaxf(mv0, 0.f)), f2bf(fmaxf(mv1, 0.f)),
                   f2bf(fmaxf(mv2, 0.f)), f2bf(fmaxf(mv3, 0.f)));
}

// ---- output GEMM: [cnt,1408]bf16 @ Wt[128][1408]bf16 + b, relu -> f32 -----
// Block: 256 thr / 4 waves (2x2). Tile 64 rows x 128 cols; wave 32x64.
// BK=64, double-buffered LDS staged via global_load_lds (width 16).
// Swizzle: LDS dest linear, global SOURCE pre-swizzled (chunk^=row&7),
// reads XOR identically (rule #21) -> fragment data identical to direct-load.
__global__ __launch_bounds__(256) void k_gemm_out(
    const unsigned short* __restrict__ H, const unsigned short* __restrict__ Wt,
    const float* __restrict__ bias, float* __restrict__ out, int Nloc) {
  __shared__ unsigned short Ab[2][64 * 64];     //  8 KB x2
  __shared__ unsigned short Bb[2][128 * 64];    // 16 KB x2
  const int tid = threadIdx.x;
  const int l = tid & 63;
  const int lr = l & 15, lg = l >> 4;
  const int w = tid >> 6, wr = w >> 1, wc = w & 1;
  const int r0 = blockIdx.x * 64;
  const int wbase = tid & 192;                  // w*64, wave-uniform

  f32x4 acc[2][4];
#pragma unroll
  for (int m = 0; m < 2; ++m)
#pragma unroll
    for (int t = 0; t < 4; ++t) {
      f32x4 z = {0.f, 0.f, 0.f, 0.f};
      acc[m][t] = z;
    }

  // ---- stage one BK=64 K-slice into buffer b ----
  auto stage = [&](int b, int kb) {
#pragma unroll
    for (int i = 0; i < 2; ++i) {               // A: 64 rows x 8 chunks
      int g = i * 256 + tid;
      int row = g >> 3, c = g & 7;
      int sc = c ^ (row & 7);
      GLD16(H + (size_t)(r0 + row) * 1408 + kb + sc * 8,
            &Ab[b][(size_t)(i * 256 + wbase) * 8]);
    }
#pragma unroll
    for (int i = 0; i < 4; ++i) {               // B: 128 rows x 8 chunks
      int g = i * 256 + tid;
      int row = g >> 3, c = g & 7;
      int sc = c ^ (row & 7);
      GLD16(Wt + (size_t)row * 1408 + kb + sc * 8,
            &Bb[b][(size_t)(i * 256 + wbase) * 8]);
    }
  };

  auto compute = [&](int b) {
#pragma unroll
    for (int kk = 0; kk < 2; ++kk) {
      int chq = kk * 4 + lg;
      bf16x8 a[2], bt[4];
#pragma unroll
      for (int m = 0; m < 2; ++m) {
        int row = wr * 32 + m * 16 + lr;
        a[m] = *(const bf16x8*)&Ab[b][(row * 8 + (chq ^ (row & 7))) * 8];
      }
#pragma unroll
      for (int t = 0; t < 4; ++t) {
        int row = wc * 64 + t * 16 + lr;
        bt[t] = *(const bf16x8*)&Bb[b][(row * 8 + (chq ^ (row & 7))) * 8];
      }
#pragma unroll
      for (int m = 0; m < 2; ++m)
#pragma unroll
        for (int t = 0; t < 4; ++t)
          acc[m][t] = __builtin_amdgcn_mfma_f32_16x16x32_bf16(
              a[m], bt[t], acc[m][t], 0, 0, 0);
    }
  };

  stage(0, 0);
  __syncthreads();
  int cur = 0;
  for (int t = 0; t < 22; ++t) {                // 22 * 64 = K = 1408
    if (t < 21) stage(cur ^ 1, (t + 1) * 64);
    compute(cur);
    __syncthreads();
    cur ^= 1;
  }

#pragma unroll
  for (int m = 0; m < 2; ++m) {
    int rb = r0 + wr * 32 + m * 16 + lg * 4;    // C/D: col=lane&15, row=lg*4+reg
#pragma unroll
    for (int t = 0; t < 4; ++t) {
      int c = wc * 64 + t * 16 + lr;
      float bbias = bias[c];
#pragma unroll
      for (int r = 0; r < 4; ++r) {
        int rr = rb + r;
        if (rr < Nloc) out[(size_t)rr * 128 + c] = fmaxf(acc[m][t][r] + bbias, 0.f);
      }
    }
  }
}

extern "C" void kernel_launch(void* const* d_in, const int* in_sizes, int n_in,
                              void* d_out, int out_size, void* d_ws,
                              size_t ws_size, hipStream_t stream) {
  const float* x_i  = (const float*)d_in[0];
  const float* x_m  = (const float*)d_in[1];
  const int*   ei   = (const int*)d_in[2];
  const float* Wi_i = (const float*)d_in[3];
  const float* bi_i = (const float*)d_in[4];
  const float* Wi_m = (const float*)d_in[5];
  const float* bi_m = (const float*)d_in[6];
  const float* Wsc  = (const float*)d_in[7];
  const float* bsc  = (const float*)d_in[8];
  const float* Wo_i = (const float*)d_in[9];
  const float* bo_i = (const float*)d_in[10];
  const float* Wo_m = (const float*)d_in[11];
  const float* bo_m = (const float*)d_in[12];
  float* out = (float*)d_out;

  int Ni = in_sizes[0] / 128, Nm = in_sizes[1] / 128, E = in_sizes[2] / 2;
  const int* es = ei;
  const int* ee = ei + E;

  char* p = (char*)d_ws;
  auto alloc = [&](size_t bytes) {
    char* q = p;
    p += (bytes + 255) & ~(size_t)255;
    return q;
  };
  unsigned short* xp_i = (unsigned short*)alloc((size_t)Ni * 256 * 2);
  unsigned short* xp_m = (unsigned short*)alloc((size_t)Nm * 256 * 2);
  float* a_i   = (float*)alloc((size_t)Ni * 4);
  float* a_m   = (float*)alloc((size_t)Nm * 4);
  float* slist = (float*)alloc((size_t)E * 4);
  int* head_i  = (int*)alloc((size_t)Ni * 4);
  int* head_m  = (int*)alloc((size_t)Nm * 4);
  int* next_i  = (int*)alloc((size_t)E * 4);
  int* next_m  = (int*)alloc((size_t)E * 4);
  unsigned short* Wt_i = (unsigned short*)alloc((size_t)128 * 1408 * 2);
  unsigned short* Wt_m = (unsigned short*)alloc((size_t)128 * 1408 * 2);

  size_t used = (size_t)(p - (char*)d_ws);
  if (used + 256 > ws_size) return;
  size_t avail = ws_size - used - 256;
  long long srows_ll = (long long)(avail / (1408 * 2));
  int maxN = (Ni > Nm ? Ni : Nm);
  int maxPad = (maxN + 127) & ~127;
  int S = (int)(srows_ll > maxPad ? maxPad : srows_ll);
  S &= ~127;
  if (S < 128) return;
  unsigned short* Hs = (unsigned short*)alloc((size_t)S * 1408 * 2);

  hipMemsetAsync(head_i, 0xFF, (size_t)Ni * 4, stream);
  hipMemsetAsync(head_m, 0xFF, (size_t)Nm * 4, stream);

  k_prep_wt<<<(1408 * 128 + 255) / 256, 256, 0, stream>>>(Wo_i, Wt_i, 1408, 128);
  k_prep_wt<<<(1408 * 128 + 255) / 256, 256, 0, stream>>>(Wo_m, Wt_m, 1408, 128);

  k_gemm_in<<<(Ni + 31) / 32, 256, 0, stream>>>(x_i, Wi_i, bi_i, Wsc, xp_i, a_i, Ni);
  k_gemm_in<<<(Nm + 31) / 32, 256, 0, stream>>>(x_m, Wi_m, bi_m, Wsc + 256, xp_m, a_m, Nm);

  k_edge<<<(E + 255) / 256, 256, 0, stream>>>(es, ee, E, a_i, a_m, bsc, slist,
                                              head_i, next_i, head_m, next_m);

  // intt side: own half of pooled cols at [0,256), gathered (mvtx) at [256,512)
  for (int base = 0; base < Ni; base += S) {
    int cnt = Ni - base; if (cnt > S) cnt = S;
    k_agg<<<(cnt + 3) / 4, 256, 0, stream>>>(x_i, xp_i, xp_m, head_i, next_i,
                                             ee, slist, Hs, base, cnt, 0, 256);
    k_gemm_out<<<(cnt + 63) / 64, 256, 0, stream>>>(Hs, Wt_i, bo_i,
                                                    out + (size_t)base * 128, cnt);
  }
  // mvtx side: gathered (intt) at [0,256), own half at [256,512)
  float* out_m = out + (size_t)Ni * 128;
  for (int base = 0; base < Nm; base += S) {
    int cnt = Nm - base; if (cnt > S) cnt = S;
    k_agg<<<(cnt + 3) / 4, 256, 0, stream>>>(x_m, xp_m, xp_i, head_m, next_m,
                                             es, slist, Hs, base, cnt, 256, 0);
    k_gemm_out<<<(cnt + 63) / 64, 256, 0, stream>>>(Hs, Wt_m, bo_m,
                                                    out_m + (size_t)base * 128, cnt);
  }
}

// Round 7
// 343.947 us; speedup vs baseline: 1.6603x; 1.3359x over previous
//
#include <hip/hip_runtime.h>

// ---------------------------------------------------------------------------
// BipartiteLayer: xp = x@W_in+b ; s = exp(-|[xp_i[s],xp_m[e]]@W_score+b|) ;
// scatter mean/max of xp_pair*s ; h = relu([x,xp,mean,max]@W_out+b)
//
// Pipeline (slab-chunked H to fit adaptive workspace):
//   k_prep_wt   : W (f32, KxN) -> Wt (N rows x K, bf16) transpose
//   k_gemm_in   : MFMA 16x16x32 bf16, K=128 one-shot LDS stage; fused bias,
//                 xp bf16 store, and a = xp.Ws via shfl butterfly + atomicAdd
//   k_edge      : per-edge score + linked-list CSR build (atomicExch)
//   per slab:
//     k_agg     : wave-per-node gather-reduce -> H slab rows (1408 bf16)
//     k_gemm_out: bf16 MFMA, 64x128 tile, BK=64 dbuf LDS via global_load_lds
// R7 fix: k_gemm_in B-staging was 8 iters (32 KB) for a 64 KB tile -> rows
// 128..255 uninit (NaN) -> relu(NaN)=0 -> all-zero output. Now 16 iters.
// ---------------------------------------------------------------------------

typedef __attribute__((ext_vector_type(8))) short bf16x8;   // 8 bf16 = 4 VGPR
typedef __attribute__((ext_vector_type(4))) float f32x4;

static __device__ __forceinline__ unsigned short f2bf(float f) {
  unsigned int u = __float_as_uint(f);
  u = (u + 0x7FFFu + ((u >> 16) & 1u)) >> 16;   // RNE
  return (unsigned short)u;
}
static __device__ __forceinline__ float bf2f(unsigned short s) {
  return __uint_as_float(((unsigned int)s) << 16);
}

#define GLD16(gp, lp)                                                        \
  __builtin_amdgcn_global_load_lds(                                          \
      (const __attribute__((address_space(1))) void*)(gp),                   \
      (__attribute__((address_space(3))) void*)(lp), 16, 0, 0)

// ---- transpose W (KxNcol f32) -> Wt[col][k] bf16 ---------------------------
__global__ void k_prep_wt(const float* __restrict__ Wo,
                          unsigned short* __restrict__ Wt, int K, int Ncol) {
  int idx = blockIdx.x * blockDim.x + threadIdx.x;
  if (idx >= K * Ncol) return;
  int k = idx / Ncol, c = idx % Ncol;
  Wt[(size_t)c * K + k] = f2bf(Wo[idx]);
}

// ---- input GEMM (MFMA): [N,128]f32 @ [128,256] -> xp bf16, a=xp.Ws --------
// Block 256 thr / 4 waves (2x2). Tile 64 rows x 256 cols; wave 32x128.
// K=128 staged once: B (Wint, 256x128 bf16) via global_load_lds w/ pre-
// swizzled source; A (x) reg-staged f32->bf16, per-lane swizzled ds_write.
__global__ __launch_bounds__(256) void k_gemm_in(
    const float* __restrict__ x, const unsigned short* __restrict__ Wint,
    const float* __restrict__ bias, const float* __restrict__ Wsc,
    unsigned short* __restrict__ xp, float* __restrict__ a_out, int N) {
  __shared__ __align__(16) unsigned short Ab[64 * 16 * 8];    // 16 KB
  __shared__ __align__(16) unsigned short Bb[256 * 16 * 8];   // 64 KB
  const int tid = threadIdx.x;
  const int l = tid & 63;
  const int lr = l & 15, lg = l >> 4;
  const int w = tid >> 6, wr = w >> 1, wc = w & 1;
  const int r0 = blockIdx.x * 64;
  const int wbase = tid & 192;                  // w*64, wave-uniform

  // B: 256 rows x 16 chunks (16B each) = 64 KB -> 16 iterations of 256 lanes
#pragma unroll
  for (int i = 0; i < 16; ++i) {
    int g = i * 256 + tid;
    int row = g >> 4, c = g & 15;
    int sc = c ^ (row & 7);
    GLD16(Wint + (size_t)row * 128 + sc * 8,
          &Bb[(size_t)(i * 256 + wbase) * 8]);
  }
  // A: 64 rows x 16 chunks, reg-stage f32->bf16, swizzled per-lane ds_write
#pragma unroll
  for (int i = 0; i < 4; ++i) {
    int g = i * 256 + tid;
    int row = g >> 4, c = g & 15;
    int ar = min(r0 + row, N - 1);
    const float* src = x + (size_t)ar * 128 + c * 8;
    float4 u = *(const float4*)src;
    float4 v = *(const float4*)(src + 4);
    bf16x8 h;
    h[0] = (short)f2bf(u.x); h[1] = (short)f2bf(u.y);
    h[2] = (short)f2bf(u.z); h[3] = (short)f2bf(u.w);
    h[4] = (short)f2bf(v.x); h[5] = (short)f2bf(v.y);
    h[6] = (short)f2bf(v.z); h[7] = (short)f2bf(v.w);
    *(bf16x8*)&Ab[(size_t)(row * 16 + (c ^ (row & 7))) * 8] = h;
  }
  __syncthreads();

  f32x4 acc[2][8];
#pragma unroll
  for (int m = 0; m < 2; ++m)
#pragma unroll
    for (int t = 0; t < 8; ++t) {
      f32x4 z = {0.f, 0.f, 0.f, 0.f};
      acc[m][t] = z;
    }
#pragma unroll
  for (int kk = 0; kk < 4; ++kk) {
    int chq = kk * 4 + lg;
    bf16x8 a[2], bt[8];
#pragma unroll
    for (int m = 0; m < 2; ++m) {
      int row = wr * 32 + m * 16 + lr;
      a[m] = *(const bf16x8*)&Ab[(row * 16 + (chq ^ (row & 7))) * 8];
    }
#pragma unroll
    for (int t = 0; t < 8; ++t) {
      int row = wc * 128 + t * 16 + lr;
      bt[t] = *(const bf16x8*)&Bb[(row * 16 + (chq ^ (row & 7))) * 8];
    }
#pragma unroll
    for (int m = 0; m < 2; ++m)
#pragma unroll
      for (int t = 0; t < 8; ++t)
        acc[m][t] = __builtin_amdgcn_mfma_f32_16x16x32_bf16(
            a[m], bt[t], acc[m][t], 0, 0, 0);
  }

  // epilogue: bias, xp store (bf16), fused a = (xp+bias) . Wsc
  float wscv[8], bb[8];
#pragma unroll
  for (int t = 0; t < 8; ++t) {
    int c = wc * 128 + t * 16 + lr;
    wscv[t] = Wsc[c];
    bb[t] = bias[c];
  }
#pragma unroll
  for (int m = 0; m < 2; ++m) {
    int rb = r0 + wr * 32 + m * 16 + lg * 4;    // C/D: col=lane&15, row=lg*4+reg
    float p0 = 0.f, p1 = 0.f, p2 = 0.f, p3 = 0.f;
#pragma unroll
    for (int t = 0; t < 8; ++t) {
      int c = wc * 128 + t * 16 + lr;
      float v0 = acc[m][t][0] + bb[t];
      float v1 = acc[m][t][1] + bb[t];
      float v2 = acc[m][t][2] + bb[t];
      float v3 = acc[m][t][3] + bb[t];
      if (rb + 0 < N) xp[(size_t)(rb + 0) * 256 + c] = f2bf(v0);
      if (rb + 1 < N) xp[(size_t)(rb + 1) * 256 + c] = f2bf(v1);
      if (rb + 2 < N) xp[(size_t)(rb + 2) * 256 + c] = f2bf(v2);
      if (rb + 3 < N) xp[(size_t)(rb + 3) * 256 + c] = f2bf(v3);
      p0 = fmaf(v0, wscv[t], p0); p1 = fmaf(v1, wscv[t], p1);
      p2 = fmaf(v2, wscv[t], p2); p3 = fmaf(v3, wscv[t], p3);
    }
#pragma unroll
    for (int off = 1; off < 16; off <<= 1) {    // butterfly within 16-lane grp
      p0 += __shfl_xor(p0, off); p1 += __shfl_xor(p1, off);
      p2 += __shfl_xor(p2, off); p3 += __shfl_xor(p3, off);
    }
    if (lr == 0) {
      if (rb + 0 < N) atomicAdd(a_out + rb + 0, p0);
      if (rb + 1 < N) atomicAdd(a_out + rb + 1, p1);
      if (rb + 2 < N) atomicAdd(a_out + rb + 2, p2);
      if (rb + 3 < N) atomicAdd(a_out + rb + 3, p3);
    }
  }
}

// ---- per-edge score + linked-list CSR -------------------------------------
__global__ void k_edge(const int* __restrict__ es, const int* __restrict__ ee,
                       int E, const float* __restrict__ a_i,
                       const float* __restrict__ a_m,
                       const float* __restrict__ bsc,
                       float* __restrict__ slist, int* __restrict__ head_i,
                       int* __restrict__ next_i, int* __restrict__ head_m,
                       int* __restrict__ next_m) {
  int e = blockIdx.x * blockDim.x + threadIdx.x;
  if (e >= E) return;
  int s = es[e], m = ee[e];
  float t = a_i[s] + a_m[m] + bsc[0];
  slist[e] = expf(-fabsf(t));
  next_i[e] = atomicExch(head_i + s, e);
  next_m[e] = atomicExch(head_m + m, e);
}

// ---- wave-per-node aggregation -> H slab row (1408 bf16) ------------------
// H = [x(128) | xp(256) | mean(512) | max(512)]
__global__ __launch_bounds__(256) void k_agg(
    const float* __restrict__ x_own, const unsigned short* __restrict__ xp_own,
    const unsigned short* __restrict__ xp_oth, const int* __restrict__ head,
    const int* __restrict__ nxt, const int* __restrict__ oth_id,
    const float* __restrict__ slist, unsigned short* __restrict__ H,
    int base, int cnt, int own_off, int oth_off) {
  int local = blockIdx.x * 4 + (threadIdx.x >> 6);
  if (local >= cnt) return;                      // wave-uniform
  int node = base + local;
  int l = threadIdx.x & 63;
  ushort4 xo = *(const ushort4*)(xp_own + (size_t)node * 256 + 4 * l);
  float xp0 = bf2f(xo.x), xp1 = bf2f(xo.y), xp2 = bf2f(xo.z), xp3 = bf2f(xo.w);
  float2 xv = *(const float2*)(x_own + (size_t)node * 128 + 2 * l);
  unsigned short* Hr = H + (size_t)local * 1408;
  *(ushort2*)(Hr + 2 * l) = make_ushort2(f2bf(xv.x), f2bf(xv.y));
  *(ushort4*)(Hr + 128 + 4 * l) = xo;

  float sum_s = 0.f, mx_s = -1e30f, mn_s = 1e30f;
  float sv0 = 0.f, sv1 = 0.f, sv2 = 0.f, sv3 = 0.f;
  float mv0 = -1e30f, mv1 = -1e30f, mv2 = -1e30f, mv3 = -1e30f;
  int dg = 0;
  for (int e = head[node]; e >= 0; e = nxt[e]) {   // uniform chain walk
    int o = oth_id[e];
    float s = slist[e];
    ushort4 ov = *(const ushort4*)(xp_oth + (size_t)o * 256 + 4 * l);
    float f0 = bf2f(ov.x), f1 = bf2f(ov.y), f2 = bf2f(ov.z), f3 = bf2f(ov.w);
    sv0 = fmaf(s, f0, sv0); sv1 = fmaf(s, f1, sv1);
    sv2 = fmaf(s, f2, sv2); sv3 = fmaf(s, f3, sv3);
    mv0 = fmaxf(mv0, s * f0); mv1 = fmaxf(mv1, s * f1);
    mv2 = fmaxf(mv2, s * f2); mv3 = fmaxf(mv3, s * f3);
    sum_s += s; mx_s = fmaxf(mx_s, s); mn_s = fminf(mn_s, s);
    ++dg;
  }
  float inv = 1.f / (float)(dg > 0 ? dg : 1);
  float ss = sum_s * inv;
  *(ushort4*)(Hr + 384 + own_off + 4 * l) = make_ushort4(
      f2bf(xp0 * ss), f2bf(xp1 * ss), f2bf(xp2 * ss), f2bf(xp3 * ss));
  *(ushort4*)(Hr + 384 + oth_off + 4 * l) = make_ushort4(
      f2bf(sv0 * inv), f2bf(sv1 * inv), f2bf(sv2 * inv), f2bf(sv3 * inv));
  float a0, a1, a2, a3;
  if (dg > 0) {
    a0 = fmaxf(fmaxf(xp0 * mx_s, xp0 * mn_s), 0.f);
    a1 = fmaxf(fmaxf(xp1 * mx_s, xp1 * mn_s), 0.f);
    a2 = fmaxf(fmaxf(xp2 * mx_s, xp2 * mn_s), 0.f);
    a3 = fmaxf(fmaxf(xp3 * mx_s, xp3 * mn_s), 0.f);
  } else {
    a0 = a1 = a2 = a3 = 0.f;
  }
  *(ushort4*)(Hr + 896 + own_off + 4 * l) =
      make_ushort4(f2bf(a0), f2bf(a1), f2bf(a2), f2bf(a3));
  *(ushort4*)(Hr + 896 + oth_off + 4 * l) =
      make_ushort4(f2bf(fmaxf(mv0, 0.f)), f2bf(fmaxf(mv1, 0.f)),
                   f2bf(fmaxf(mv2, 0.f)), f2bf(fmaxf(mv3, 0.f)));
}

// ---- output GEMM: [cnt,1408]bf16 @ Wt[128][1408]bf16 + b, relu -> f32 -----
__global__ __launch_bounds__(256) void k_gemm_out(
    const unsigned short* __restrict__ H, const unsigned short* __restrict__ Wt,
    const float* __restrict__ bias, float* __restrict__ out, int Nloc) {
  __shared__ unsigned short Ab[2][64 * 64];     //  8 KB x2
  __shared__ unsigned short Bb[2][128 * 64];    // 16 KB x2
  const int tid = threadIdx.x;
  const int l = tid & 63;
  const int lr = l & 15, lg = l >> 4;
  const int w = tid >> 6, wr = w >> 1, wc = w & 1;
  const int r0 = blockIdx.x * 64;
  const int wbase = tid & 192;                  // w*64, wave-uniform

  f32x4 acc[2][4];
#pragma unroll
  for (int m = 0; m < 2; ++m)
#pragma unroll
    for (int t = 0; t < 4; ++t) {
      f32x4 z = {0.f, 0.f, 0.f, 0.f};
      acc[m][t] = z;
    }

  auto stage = [&](int b, int kb) {
#pragma unroll
    for (int i = 0; i < 2; ++i) {               // A: 64 rows x 8 chunks
      int g = i * 256 + tid;
      int row = g >> 3, c = g & 7;
      int sc = c ^ (row & 7);
      GLD16(H + (size_t)(r0 + row) * 1408 + kb + sc * 8,
            &Ab[b][(size_t)(i * 256 + wbase) * 8]);
    }
#pragma unroll
    for (int i = 0; i < 4; ++i) {               // B: 128 rows x 8 chunks
      int g = i * 256 + tid;
      int row = g >> 3, c = g & 7;
      int sc = c ^ (row & 7);
      GLD16(Wt + (size_t)row * 1408 + kb + sc * 8,
            &Bb[b][(size_t)(i * 256 + wbase) * 8]);
    }
  };

  auto compute = [&](int b) {
#pragma unroll
    for (int kk = 0; kk < 2; ++kk) {
      int chq = kk * 4 + lg;
      bf16x8 a[2], bt[4];
#pragma unroll
      for (int m = 0; m < 2; ++m) {
        int row = wr * 32 + m * 16 + lr;
        a[m] = *(const bf16x8*)&Ab[b][(row * 8 + (chq ^ (row & 7))) * 8];
      }
#pragma unroll
      for (int t = 0; t < 4; ++t) {
        int row = wc * 64 + t * 16 + lr;
        bt[t] = *(const bf16x8*)&Bb[b][(row * 8 + (chq ^ (row & 7))) * 8];
      }
#pragma unroll
      for (int m = 0; m < 2; ++m)
#pragma unroll
        for (int t = 0; t < 4; ++t)
          acc[m][t] = __builtin_amdgcn_mfma_f32_16x16x32_bf16(
              a[m], bt[t], acc[m][t], 0, 0, 0);
    }
  };

  stage(0, 0);
  __syncthreads();
  int cur = 0;
  for (int t = 0; t < 22; ++t) {                // 22 * 64 = K = 1408
    if (t < 21) stage(cur ^ 1, (t + 1) * 64);
    compute(cur);
    __syncthreads();
    cur ^= 1;
  }

#pragma unroll
  for (int m = 0; m < 2; ++m) {
    int rb = r0 + wr * 32 + m * 16 + lg * 4;    // C/D: col=lane&15, row=lg*4+reg
#pragma unroll
    for (int t = 0; t < 4; ++t) {
      int c = wc * 64 + t * 16 + lr;
      float bbias = bias[c];
#pragma unroll
      for (int r = 0; r < 4; ++r) {
        int rr = rb + r;
        if (rr < Nloc) out[(size_t)rr * 128 + c] = fmaxf(acc[m][t][r] + bbias, 0.f);
      }
    }
  }
}

extern "C" void kernel_launch(void* const* d_in, const int* in_sizes, int n_in,
                              void* d_out, int out_size, void* d_ws,
                              size_t ws_size, hipStream_t stream) {
  const float* x_i  = (const float*)d_in[0];
  const float* x_m  = (const float*)d_in[1];
  const int*   ei   = (const int*)d_in[2];
  const float* Wi_i = (const float*)d_in[3];
  const float* bi_i = (const float*)d_in[4];
  const float* Wi_m = (const float*)d_in[5];
  const float* bi_m = (const float*)d_in[6];
  const float* Wsc  = (const float*)d_in[7];
  const float* bsc  = (const float*)d_in[8];
  const float* Wo_i = (const float*)d_in[9];
  const float* bo_i = (const float*)d_in[10];
  const float* Wo_m = (const float*)d_in[11];
  const float* bo_m = (const float*)d_in[12];
  float* out = (float*)d_out;

  int Ni = in_sizes[0] / 128, Nm = in_sizes[1] / 128, E = in_sizes[2] / 2;
  const int* es = ei;
  const int* ee = ei + E;

  char* p = (char*)d_ws;
  auto alloc = [&](size_t bytes) {
    char* q = p;
    p += (bytes + 255) & ~(size_t)255;
    return q;
  };
  unsigned short* xp_i = (unsigned short*)alloc((size_t)Ni * 256 * 2);
  unsigned short* xp_m = (unsigned short*)alloc((size_t)Nm * 256 * 2);
  float* a_i   = (float*)alloc((size_t)Ni * 4);
  float* a_m   = (float*)alloc((size_t)Nm * 4);
  float* slist = (float*)alloc((size_t)E * 4);
  int* head_i  = (int*)alloc((size_t)Ni * 4);
  int* head_m  = (int*)alloc((size_t)Nm * 4);
  int* next_i  = (int*)alloc((size_t)E * 4);
  int* next_m  = (int*)alloc((size_t)E * 4);
  unsigned short* Wt_i = (unsigned short*)alloc((size_t)128 * 1408 * 2);
  unsigned short* Wt_m = (unsigned short*)alloc((size_t)128 * 1408 * 2);
  unsigned short* Wint_i = (unsigned short*)alloc((size_t)256 * 128 * 2);
  unsigned short* Wint_m = (unsigned short*)alloc((size_t)256 * 128 * 2);

  size_t used = (size_t)(p - (char*)d_ws);
  if (used + 256 > ws_size) return;
  size_t avail = ws_size - used - 256;
  long long srows_ll = (long long)(avail / (1408 * 2));
  int maxN = (Ni > Nm ? Ni : Nm);
  int maxPad = (maxN + 127) & ~127;
  int S = (int)(srows_ll > maxPad ? maxPad : srows_ll);
  S &= ~127;
  if (S < 128) return;
  unsigned short* Hs = (unsigned short*)alloc((size_t)S * 1408 * 2);

  hipMemsetAsync(head_i, 0xFF, (size_t)Ni * 4, stream);
  hipMemsetAsync(head_m, 0xFF, (size_t)Nm * 4, stream);
  hipMemsetAsync(a_i, 0, (size_t)Ni * 4, stream);
  hipMemsetAsync(a_m, 0, (size_t)Nm * 4, stream);

  k_prep_wt<<<(1408 * 128 + 255) / 256, 256, 0, stream>>>(Wo_i, Wt_i, 1408, 128);
  k_prep_wt<<<(1408 * 128 + 255) / 256, 256, 0, stream>>>(Wo_m, Wt_m, 1408, 128);
  k_prep_wt<<<(128 * 256 + 255) / 256, 256, 0, stream>>>(Wi_i, Wint_i, 128, 256);
  k_prep_wt<<<(128 * 256 + 255) / 256, 256, 0, stream>>>(Wi_m, Wint_m, 128, 256);

  k_gemm_in<<<(Ni + 63) / 64, 256, 0, stream>>>(x_i, Wint_i, bi_i, Wsc, xp_i, a_i, Ni);
  k_gemm_in<<<(Nm + 63) / 64, 256, 0, stream>>>(x_m, Wint_m, bi_m, Wsc + 256, xp_m, a_m, Nm);

  k_edge<<<(E + 255) / 256, 256, 0, stream>>>(es, ee, E, a_i, a_m, bsc, slist,
                                              head_i, next_i, head_m, next_m);

  // intt side: own half of pooled cols at [0,256), gathered (mvtx) at [256,512)
  for (int base = 0; base < Ni; base += S) {
    int cnt = Ni - base; if (cnt > S) cnt = S;
    k_agg<<<(cnt + 3) / 4, 256, 0, stream>>>(x_i, xp_i, xp_m, head_i, next_i,
                                             ee, slist, Hs, base, cnt, 0, 256);
    k_gemm_out<<<(cnt + 63) / 64, 256, 0, stream>>>(Hs, Wt_i, bo_i,
                                                    out + (size_t)base * 128, cnt);
  }
  // mvtx side: gathered (intt) at [0,256), own half at [256,512)
  float* out_m = out + (size_t)Ni * 128;
  for (int base = 0; base < Nm; base += S) {
    int cnt = Nm - base; if (cnt > S) cnt = S;
    k_agg<<<(cnt + 3) / 4, 256, 0, stream>>>(x_m, xp_m, xp_i, head_m, next_m,
                                             es, slist, Hs, base, cnt, 256, 0);
    k_gemm_out<<<(cnt + 63) / 64, 256, 0, stream>>>(Hs, Wt_m, bo_m,
                                                    out_m + (size_t)base * 128, cnt);
  }
}